// Round 1
// baseline (1191.914 us; speedup 1.0000x reference)
//
#include <hip/hip_runtime.h>
#include <cstdint>
#include <cstddef>

#define T_TOK 2048
#define H_DIM 2048
#define E_NUM 8
#define F_DIM 4096

typedef __attribute__((ext_vector_type(8))) short bh8;    // 8 bf16 (4 VGPRs)
typedef __attribute__((ext_vector_type(4))) float f32x4;  // MFMA C/D

static __device__ __forceinline__ unsigned short f2bf(float f) {
  union { float f; unsigned int u; } v; v.f = f;
  unsigned int r = v.u + 0x7FFFu + ((v.u >> 16) & 1u);  // RNE
  return (unsigned short)(r >> 16);
}

// async global->LDS, 16B per lane, wave-uniform LDS base + lane*16 (linear dest)
static __device__ __forceinline__ void gload16(const unsigned short* g, unsigned short* l) {
  __builtin_amdgcn_global_load_lds(
      (const __attribute__((address_space(1))) unsigned int*)g,
      (__attribute__((address_space(3))) unsigned int*)l,
      16, 0, 0);
}

// swizzled LDS fragment read: tile row stride 64 elems (128B); col in elements
// (multiple of 8). XOR on bits 3..5 of element index == byte ^ ((row&7)<<4).
static __device__ __forceinline__ bh8 ldsw(const unsigned short* base, int row, int col) {
  return *(const bh8*)(base + row * 64 + (col ^ ((row & 7) << 3)));
}

// ---------------- fp32 -> bf16 elementwise (x, w1, w3) ----------------
__global__ __launch_bounds__(256) void convert_f32_bf16(const float* __restrict__ src,
                                                        unsigned short* __restrict__ dst) {
  size_t i = ((size_t)blockIdx.x * 256 + threadIdx.x) * 4;
  float4 v = *(const float4*)(src + i);
  ushort4 o;
  o.x = f2bf(v.x); o.y = f2bf(v.y); o.z = f2bf(v.z); o.w = f2bf(v.w);
  *(ushort4*)(dst + i) = o;
}

// ---------------- W2 [E*F][H] fp32 -> W2t [E][H][F] bf16 ----------------
__global__ __launch_bounds__(256) void transpose_w2(const float* __restrict__ w2,
                                                    unsigned short* __restrict__ w2t) {
  // grid: (H/64, F/64, E)
  const int e = blockIdx.z;
  const int f0 = blockIdx.y * 64;
  const int h0 = blockIdx.x * 64;
  __shared__ float tile[64][65];
  const int tid = threadIdx.x;
  const int r = tid >> 4;          // 0..15
  const int c4 = (tid & 15) * 4;   // 0..60
#pragma unroll
  for (int l = 0; l < 4; l++) {
    int f = r + l * 16;
    float4 v = *(const float4*)(w2 + ((size_t)(e * F_DIM + f0 + f)) * H_DIM + h0 + c4);
    tile[f][c4 + 0] = v.x; tile[f][c4 + 1] = v.y; tile[f][c4 + 2] = v.z; tile[f][c4 + 3] = v.w;
  }
  __syncthreads();
#pragma unroll
  for (int l = 0; l < 4; l++) {
    int h = r + l * 16;
    ushort4 o;
    o.x = f2bf(tile[c4 + 0][h]);
    o.y = f2bf(tile[c4 + 1][h]);
    o.z = f2bf(tile[c4 + 2][h]);
    o.w = f2bf(tile[c4 + 3][h]);
    *(ushort4*)(w2t + ((size_t)e * H_DIM + h0 + h) * F_DIM + f0 + c4) = o;
  }
}

// ---------------- gating + top-2 routing ----------------
__global__ __launch_bounds__(64) void gate_topk(const float* __restrict__ x,
                                                const float* __restrict__ gw,
                                                int* __restrict__ counts,
                                                int* __restrict__ etok,
                                                float* __restrict__ ewts) {
  const int t = blockIdx.x;
  const int lane = threadIdx.x;
  float acc[E_NUM];
#pragma unroll
  for (int e = 0; e < E_NUM; e++) acc[e] = 0.f;
  const float* xr = x + (size_t)t * H_DIM;
  for (int i = lane; i < H_DIM; i += 64) {
    float xv = xr[i];
#pragma unroll
    for (int e = 0; e < E_NUM; e++) acc[e] += xv * gw[e * H_DIM + i];
  }
#pragma unroll
  for (int e = 0; e < E_NUM; e++) {
#pragma unroll
    for (int off = 32; off > 0; off >>= 1) acc[e] += __shfl_xor(acc[e], off, 64);
  }
  if (lane == 0) {
    int e0 = 0;
#pragma unroll
    for (int e = 1; e < E_NUM; e++) if (acc[e] > acc[e0]) e0 = e;  // strict >: lowest idx on tie
    int e1 = (e0 == 0) ? 1 : 0;
#pragma unroll
    for (int e = 0; e < E_NUM; e++) {
      if (e != e0 && acc[e] > acc[e1]) e1 = e;
    }
    float z = __expf(acc[e1] - acc[e0]);
    float w0 = 1.f / (1.f + z);
    float w1v = z / (1.f + z);
    int p0 = atomicAdd(&counts[e0], 1);
    etok[e0 * T_TOK + p0] = t; ewts[e0 * T_TOK + p0] = w0;
    int p1 = atomicAdd(&counts[e1], 1);
    etok[e1 * T_TOK + p1] = t; ewts[e1 * T_TOK + p1] = w1v;
  }
}

// ---------------- exclusive scan of 8 counts ----------------
__global__ void scan_offsets(const int* __restrict__ counts, int* __restrict__ offsets) {
  if (threadIdx.x == 0 && blockIdx.x == 0) {
    int run = 0;
    for (int e = 0; e < E_NUM; e++) { offsets[e] = run; run += counts[e]; }
  }
}

// ---------------- GEMM1: inter = silu(x@W1^T) * (x@W3^T) ----------------
// block tile 128(M) x 64(N) x 64(K); 4 waves 2x2; wave tile 64x32 per matrix
// global_load_lds staging, linear LDS + XOR swizzle (source-side + read-side)
template<bool BW>
__global__ __launch_bounds__(256) void gemm1_swiglu(
    const unsigned short* __restrict__ xb,
    const float* __restrict__ w1f, const float* __restrict__ w3f,
    const unsigned short* __restrict__ w1b, const unsigned short* __restrict__ w3b,
    const int* __restrict__ counts, const int* __restrict__ offsets,
    const int* __restrict__ etok,
    unsigned short* __restrict__ inter)
{
  const int e = blockIdx.z, mt = blockIdx.y, nt = blockIdx.x;
  const int rem = counts[e] - mt * 128;
  if (rem <= 0) return;
  const int tid = threadIdx.x;
  const int lane = tid & 63;
  const int wv = tid >> 6;

  __shared__ alignas(16) unsigned short As[128][64];   // 16 KB, linear
  __shared__ alignas(16) unsigned short B1s[64][64];   // 8 KB
  __shared__ alignas(16) unsigned short B3s[64][64];   // 8 KB

  const int tokbase = e * T_TOK + mt * 128;

  // per-lane pre-swizzled global source pointers (column-group g = (lane&7)^(row&7))
  const unsigned short* aptr[4];
#pragma unroll
  for (int l = 0; l < 4; l++) {
    int row = wv * 32 + l * 8 + (lane >> 3);
    int tok = etok[tokbase + (row < rem ? row : rem - 1)];
    int g = (lane & 7) ^ (row & 7);
    aptr[l] = xb + (size_t)tok * H_DIM + g * 8;
  }
  const unsigned short *b1ptr[2], *b3ptr[2];
  if constexpr (BW) {
#pragma unroll
    for (int l = 0; l < 2; l++) {
      int row = wv * 16 + l * 8 + (lane >> 3);
      int g = (lane & 7) ^ (row & 7);
      size_t roff = ((size_t)(e * F_DIM + nt * 64 + row)) * H_DIM + g * 8;
      b1ptr[l] = w1b + roff;
      b3ptr[l] = w3b + roff;
    }
  }

  const int wm = (wv >> 1) * 64;
  const int wn = (wv & 1) * 32;
  const int mrow = lane & 15;
  const int qk = (lane >> 4) * 8;

  f32x4 acc1[4][2], acc3[4][2];
#pragma unroll
  for (int i = 0; i < 4; i++)
#pragma unroll
    for (int j = 0; j < 2; j++) { acc1[i][j] = (f32x4)(0.f); acc3[i][j] = (f32x4)(0.f); }

  for (int k0 = 0; k0 < H_DIM; k0 += 64) {
#pragma unroll
    for (int l = 0; l < 4; l++) gload16(aptr[l] + k0, &As[wv * 32 + l * 8][0]);
    if constexpr (BW) {
#pragma unroll
      for (int l = 0; l < 2; l++) {
        gload16(b1ptr[l] + k0, &B1s[wv * 16 + l * 8][0]);
        gload16(b3ptr[l] + k0, &B3s[wv * 16 + l * 8][0]);
      }
    } else {
      // fallback: inline fp32->bf16 conversion, swizzled ds_write
      const int br = tid >> 2;            // 0..63
#pragma unroll
      for (int l = 0; l < 4; l++) {
        int c4 = ((tid & 3) + l * 4) * 4; // 0..60
        size_t wrow = ((size_t)(e * F_DIM + nt * 64 + br)) * H_DIM + k0 + c4;
        float4 v = *(const float4*)(w1f + wrow);
        float4 u = *(const float4*)(w3f + wrow);
        int eo = br * 64 + (c4 ^ ((br & 7) << 3));
        ushort4 o;
        o.x = f2bf(v.x); o.y = f2bf(v.y); o.z = f2bf(v.z); o.w = f2bf(v.w);
        *(ushort4*)(&B1s[0][0] + eo) = o;
        o.x = f2bf(u.x); o.y = f2bf(u.y); o.z = f2bf(u.z); o.w = f2bf(u.w);
        *(ushort4*)(&B3s[0][0] + eo) = o;
      }
    }
    __syncthreads();
    const unsigned short* Ab = &As[0][0];
    const unsigned short* B1b = &B1s[0][0];
    const unsigned short* B3b = &B3s[0][0];
#pragma unroll
    for (int s = 0; s < 2; s++) {
      const int cs = qk | (s << 5);
      bh8 a[4], b1[2], b3[2];
#pragma unroll
      for (int i = 0; i < 4; i++) a[i] = ldsw(Ab, wm + i * 16 + mrow, cs);
#pragma unroll
      for (int j = 0; j < 2; j++) {
        b1[j] = ldsw(B1b, wn + j * 16 + mrow, cs);
        b3[j] = ldsw(B3b, wn + j * 16 + mrow, cs);
      }
#pragma unroll
      for (int i = 0; i < 4; i++)
#pragma unroll
        for (int j = 0; j < 2; j++) {
          acc1[i][j] = __builtin_amdgcn_mfma_f32_16x16x32_bf16(a[i], b1[j], acc1[i][j], 0, 0, 0);
          acc3[i][j] = __builtin_amdgcn_mfma_f32_16x16x32_bf16(a[i], b3[j], acc3[i][j], 0, 0, 0);
        }
    }
    __syncthreads();
  }

  const int off = offsets[e];
  const int quad = lane >> 4;
#pragma unroll
  for (int i = 0; i < 4; i++) {
#pragma unroll
    for (int r = 0; r < 4; r++) {
      int m = wm + i * 16 + quad * 4 + r;
      if (m < rem) {
        size_t rowbase = (size_t)(off + mt * 128 + m) * F_DIM + nt * 64 + wn + mrow;
#pragma unroll
        for (int j = 0; j < 2; j++) {
          float c1 = acc1[i][j][r], c3 = acc3[i][j][r];
          float s = c1 / (1.f + __expf(-c1));
          inter[rowbase + j * 16] = f2bf(s * c3);
        }
      }
    }
  }
}

// ---------------- GEMM2: out[t,:] += wgt * (inter_row @ W2_e) ----------------
// block tile 128(M) x 128(N) x 64(K); 4 waves 2x2; wave tile 64x64
template<bool BW>
__global__ __launch_bounds__(256) void gemm2_scatter(
    const unsigned short* __restrict__ inter,  // [4096][F] bf16
    const float* __restrict__ w2f,             // [E*F][H] fp32 (fallback)
    const unsigned short* __restrict__ w2t,    // [E][H][F] bf16 (fast)
    const int* __restrict__ counts, const int* __restrict__ offsets,
    const int* __restrict__ etok, const float* __restrict__ ewts,
    float* __restrict__ out)                   // [T][H] fp32, pre-zeroed
{
  const int e = blockIdx.z, mt = blockIdx.y, nt = blockIdx.x;
  const int rem = counts[e] - mt * 128;
  if (rem <= 0) return;
  const int tid = threadIdx.x;
  const int lane = tid & 63;
  const int wv = tid >> 6;

  __shared__ alignas(16) unsigned short As[128][64];  // 16 KB
  __shared__ alignas(16) unsigned short Bs[128][64];  // 16 KB, Bs[n][k]

  const int off = offsets[e];

  const unsigned short* aptr[4];
#pragma unroll
  for (int l = 0; l < 4; l++) {
    int row = wv * 32 + l * 8 + (lane >> 3);
    int gr = off + mt * 128 + (row < rem ? row : rem - 1);
    int g = (lane & 7) ^ (row & 7);
    aptr[l] = inter + (size_t)gr * F_DIM + g * 8;
  }
  const unsigned short* bptr[4];
  if constexpr (BW) {
#pragma unroll
    for (int l = 0; l < 4; l++) {
      int row = wv * 32 + l * 8 + (lane >> 3);
      int g = (lane & 7) ^ (row & 7);
      bptr[l] = w2t + ((size_t)e * H_DIM + nt * 128 + row) * F_DIM + g * 8;
    }
  }

  const int wm = (wv >> 1) * 64;
  const int wn = (wv & 1) * 64;
  const int mrow = lane & 15;
  const int qk = (lane >> 4) * 8;

  f32x4 acc[4][4];
#pragma unroll
  for (int i = 0; i < 4; i++)
#pragma unroll
    for (int j = 0; j < 4; j++) acc[i][j] = (f32x4)(0.f);

  for (int k0 = 0; k0 < F_DIM; k0 += 64) {
#pragma unroll
    for (int l = 0; l < 4; l++) gload16(aptr[l] + k0, &As[wv * 32 + l * 8][0]);
    if constexpr (BW) {
#pragma unroll
      for (int l = 0; l < 4; l++) gload16(bptr[l] + k0, &Bs[wv * 32 + l * 8][0]);
    } else {
      // fallback: transpose-stage w2f [k][n] -> Bs[n][k], swizzled scalar writes
      const int bkr = tid >> 5;         // 0..7
      const int bc4 = (tid & 31) * 4;   // 0..124
      unsigned short* Bb = &Bs[0][0];
#pragma unroll
      for (int l = 0; l < 8; l++) {
        int k = bkr + l * 8;            // 0..63
        float4 v = *(const float4*)(w2f + ((size_t)(e * F_DIM + k0 + k)) * H_DIM + nt * 128 + bc4);
        int n0 = bc4;
        Bb[(n0 + 0) * 64 + (k ^ (((n0 + 0) & 7) << 3))] = f2bf(v.x);
        Bb[(n0 + 1) * 64 + (k ^ (((n0 + 1) & 7) << 3))] = f2bf(v.y);
        Bb[(n0 + 2) * 64 + (k ^ (((n0 + 2) & 7) << 3))] = f2bf(v.z);
        Bb[(n0 + 3) * 64 + (k ^ (((n0 + 3) & 7) << 3))] = f2bf(v.w);
      }
    }
    __syncthreads();
    const unsigned short* Ab = &As[0][0];
    const unsigned short* Bb = &Bs[0][0];
#pragma unroll
    for (int s = 0; s < 2; s++) {
      const int cs = qk | (s << 5);
      bh8 a[4], b[4];
#pragma unroll
      for (int i = 0; i < 4; i++) a[i] = ldsw(Ab, wm + i * 16 + mrow, cs);
#pragma unroll
      for (int j = 0; j < 4; j++) b[j] = ldsw(Bb, wn + j * 16 + mrow, cs);
#pragma unroll
      for (int i = 0; i < 4; i++)
#pragma unroll
        for (int j = 0; j < 4; j++)
          acc[i][j] = __builtin_amdgcn_mfma_f32_16x16x32_bf16(a[i], b[j], acc[i][j], 0, 0, 0);
    }
    __syncthreads();
  }

  const int quad = lane >> 4;
#pragma unroll
  for (int i = 0; i < 4; i++) {
#pragma unroll
    for (int r = 0; r < 4; r++) {
      int m = wm + i * 16 + quad * 4 + r;
      if (m < rem) {
        int slot = e * T_TOK + mt * 128 + m;
        int t = etok[slot];
        float wgt = ewts[slot];
        float* orow = out + (size_t)t * H_DIM + nt * 128 + wn + mrow;
#pragma unroll
        for (int j = 0; j < 4; j++) unsafeAtomicAdd(orow + j * 16, wgt * acc[i][j][r]);
      }
    }
  }
}

extern "C" void kernel_launch(void* const* d_in, const int* in_sizes, int n_in,
                              void* d_out, int out_size, void* d_ws, size_t ws_size,
                              hipStream_t stream) {
  const float* x  = (const float*)d_in[0];
  const float* gw = (const float*)d_in[1];
  const float* w1 = (const float*)d_in[2];
  const float* w2 = (const float*)d_in[3];
  const float* w3 = (const float*)d_in[4];
  float* out = (float*)d_out;

  char* ws = (char*)d_ws;
  int* counts   = (int*)(ws + 0);
  int* offsets  = (int*)(ws + 64);
  int* etok     = (int*)(ws + 128);                    // 64 KB
  float* ewts   = (float*)(ws + 128 + 65536);          // 64 KB
  unsigned short* xb    = (unsigned short*)(ws + 256 * 1024);                        // 8 MB
  unsigned short* inter = (unsigned short*)(ws + 256 * 1024 + 8 * 1024 * 1024);      // 32 MB
  const size_t BASE_END = 256 * 1024 + 8ull * 1024 * 1024 + 33554432ull;             // 42,205,184
  const size_t WB = (size_t)E_NUM * F_DIM * H_DIM * 2;                               // 128 MB each
  unsigned short* w2t = (unsigned short*)(ws + BASE_END);
  unsigned short* w1b = (unsigned short*)(ws + BASE_END + WB);
  unsigned short* w3b = (unsigned short*)(ws + BASE_END + 2 * WB);
  const size_t MID  = BASE_END + WB;       // w2t fits
  const size_t FULL = BASE_END + 3 * WB;   // + w1b,w3b
  const bool tA = ws_size >= MID;
  const bool tB = ws_size >= FULL;

  hipMemsetAsync(counts, 0, 64, stream);
  hipMemsetAsync(d_out, 0, (size_t)T_TOK * H_DIM * sizeof(float), stream);

  convert_f32_bf16<<<(T_TOK * H_DIM) / (256 * 4), 256, 0, stream>>>(x, xb);
  gate_topk<<<T_TOK, 64, 0, stream>>>(x, gw, counts, etok, ewts);
  scan_offsets<<<1, 64, 0, stream>>>(counts, offsets);

  const int WBLK = (E_NUM * F_DIM * H_DIM) / (256 * 4);  // 65536
  if (tB) {
    convert_f32_bf16<<<WBLK, 256, 0, stream>>>(w1, w1b);
    convert_f32_bf16<<<WBLK, 256, 0, stream>>>(w3, w3b);
  }
  if (tA) {
    transpose_w2<<<dim3(H_DIM / 64, F_DIM / 64, E_NUM), 256, 0, stream>>>(w2, w2t);
  }

  if (tB) {
    gemm1_swiglu<true><<<dim3(F_DIM / 64, 16, E_NUM), 256, 0, stream>>>(
        xb, w1, w3, w1b, w3b, counts, offsets, etok, inter);
  } else {
    gemm1_swiglu<false><<<dim3(F_DIM / 64, 16, E_NUM), 256, 0, stream>>>(
        xb, w1, w3, w1b, w3b, counts, offsets, etok, inter);
  }
  if (tA) {
    gemm2_scatter<true><<<dim3(H_DIM / 128, 16, E_NUM), 256, 0, stream>>>(
        inter, w2, w2t, counts, offsets, etok, ewts, out);
  } else {
    gemm2_scatter<false><<<dim3(H_DIM / 128, 16, E_NUM), 256, 0, stream>>>(
        inter, w2, w2t, counts, offsets, etok, ewts, out);
  }
}